// Round 6
// baseline (180.860 us; speedup 1.0000x reference)
//
#include <hip/hip_runtime.h>
#include <hip/hip_bf16.h>
#include <cstdint>

#define V_N    50000
#define C_N    128
#define COUT_N 256
#define DEG_N  16
#define K2_N   256   // 2*C

typedef short bf16x8 __attribute__((ext_vector_type(8)));
typedef float f32x4  __attribute__((ext_vector_type(4)));

__device__ __forceinline__ unsigned short f2bf(float f) {
    union { float f; unsigned u; } a; a.f = f;
    unsigned r = a.u + 0x7fffu + ((a.u >> 16) & 1u);   // round-to-nearest-even
    return (unsigned short)(r >> 16);
}
__device__ __forceinline__ float bflo(unsigned p) {
    union { unsigned u; float f; } a; a.u = p << 16; return a.f;
}
__device__ __forceinline__ float bfhi(unsigned p) {
    union { unsigned u; float f; } a; a.u = p & 0xffff0000u; return a.f;
}

// Kernel weights -> bf16, pre-swizzled into MFMA B-fragment order:
// element (n,k) -> bt[ ((nb*8+ks)*4+kk)*128 + nr*8 + kp ]
//   nb=n>>4, nr=n&15, ks=k>>5, kk=(k>>3)&3, kp=k&7
// so a (nf,ks) fragment load is lane-linear 16B -> one coalesced 1KB instr.
__global__ void prep_bt_kernel(const float* __restrict__ kern,
                               unsigned short* __restrict__ bt) {
    const int k = blockIdx.x;    // 0..255
    const int n = threadIdx.x;   // 0..255
    const int idx = (((n >> 4) * 8 + (k >> 5)) * 4 + ((k >> 3) & 3)) * 128
                  + (n & 15) * 8 + (k & 7);
    bt[idx] = f2bf(kern[k * COUT_N + n]);
}

// Convert data fp32 -> bf16 table (halves gather bytes). 12.8MB in d_ws.
__global__ __launch_bounds__(256)
void prep_data_kernel(const float* __restrict__ data,
                      unsigned short* __restrict__ db) {
    const int i = blockIdx.x * 256 + threadIdx.x;        // unit of 8 floats; grid exact
    const float4 f0 = *reinterpret_cast<const float4*>(data + (size_t)i * 8);
    const float4 f1 = *reinterpret_cast<const float4*>(data + (size_t)i * 8 + 4);
    union { unsigned short h[8]; uint4 q; } o;
    o.h[0] = f2bf(f0.x); o.h[1] = f2bf(f0.y); o.h[2] = f2bf(f0.z); o.h[3] = f2bf(f0.w);
    o.h[4] = f2bf(f1.x); o.h[5] = f2bf(f1.y); o.h[6] = f2bf(f1.z); o.h[7] = f2bf(f1.w);
    *reinterpret_cast<uint4*>(db + (size_t)i * 8) = o.q;
}

// Fused: quad-gather weighted aggregation -> bf16 A tile in LDS -> MFMA.
// Round 6: 256 threads (4 waves), BM = 32 -> grid 1563 (~6 blocks/CU resident).
// Rationale: per-wave gather MLP is pinned at ~4-6 by the allocator's 64-VGPR
// bucket (r4/r5); the remaining lever is resident-wave count. 256-thr blocks
// empirically fill CUs ~2x better than 512-thr (r2: 0.79x of cap vs r4: 0.37x).
// LDS = A tile 32x512B = 16KB, XOR-swizzled. Each 16-lane group owns rows
// {gg, gg+16}; gathers are 1KB/wave coalesced uint4; edge meta as uint4/float4.
// Phase 2: wave w owns a 32x64 tile (wn=wid), B-frags from pre-swizzled Bt.
__global__ __launch_bounds__(256, 6)
void dgc_fused_kernel(const unsigned short* __restrict__ db,
                      const int* __restrict__ edge_dst,
                      const float* __restrict__ edge_w,
                      const unsigned short* __restrict__ btg,
                      const float* __restrict__ bias,
                      float* __restrict__ out) {
    __shared__ __align__(16) char Asm[32 * 512];   // 16KB

    const int tid  = threadIdx.x;
    const int lane = tid & 63;
    const int wid  = __builtin_amdgcn_readfirstlane(tid >> 6);  // 0..3
    const int m0   = blockIdx.x * 32;
    const int g    = lane >> 4;     // group in wave / k-slice index
    const int c    = lane & 15;     // 16B chunk index

    // ---------------- Phase 1: aggregate 2 rows per 16-lane group ----------------
    const int row0 = wid * 4 + g;        // 0..15
    const int row1 = row0 + 16;          // 16..31
    const int cv0  = min(m0 + row0, V_N - 1);   // clamp: tail rows never stored
    const int cv1  = min(m0 + row1, V_N - 1);

    const uint4*  ed0 = reinterpret_cast<const uint4*>(edge_dst + (size_t)cv0 * DEG_N);
    const float4* ew0 = reinterpret_cast<const float4*>(edge_w  + (size_t)cv0 * DEG_N);
    const uint4*  ed1 = reinterpret_cast<const uint4*>(edge_dst + (size_t)cv1 * DEG_N);
    const float4* ew1 = reinterpret_cast<const float4*>(edge_w  + (size_t)cv1 * DEG_N);

    const uint4 x0 = *reinterpret_cast<const uint4*>(db + (size_t)cv0 * C_N + c * 8);
    const uint4 x1 = *reinterpret_cast<const uint4*>(db + (size_t)cv1 * C_N + c * 8);

    float s0[8], s1[8];
    #pragma unroll
    for (int i = 0; i < 8; ++i) { s0[i] = 0.f; s1[i] = 0.f; }
    float Ws0 = 0.f, Ws1 = 0.f;

#define GATH(S, J, WK)                                                        \
    do {                                                                      \
        const uint4 rr = *reinterpret_cast<const uint4*>(                     \
            db + (size_t)(J) * C_N + c * 8);                                  \
        S[0] = fmaf((WK), bflo(rr.x), S[0]);                                  \
        S[1] = fmaf((WK), bfhi(rr.x), S[1]);                                  \
        S[2] = fmaf((WK), bflo(rr.y), S[2]);                                  \
        S[3] = fmaf((WK), bfhi(rr.y), S[3]);                                  \
        S[4] = fmaf((WK), bflo(rr.z), S[4]);                                  \
        S[5] = fmaf((WK), bfhi(rr.z), S[5]);                                  \
        S[6] = fmaf((WK), bflo(rr.w), S[6]);                                  \
        S[7] = fmaf((WK), bfhi(rr.w), S[7]);                                  \
    } while (0)

    #pragma unroll
    for (int kq = 0; kq < 4; ++kq) {
        const uint4  d0 = ed0[kq];
        const float4 w0 = ew0[kq];
        const uint4  d1 = ed1[kq];
        const float4 w1 = ew1[kq];
        GATH(s0, d0.x, w0.x);
        GATH(s0, d0.y, w0.y);
        GATH(s0, d0.z, w0.z);
        GATH(s0, d0.w, w0.w);
        GATH(s1, d1.x, w1.x);
        GATH(s1, d1.y, w1.y);
        GATH(s1, d1.z, w1.z);
        GATH(s1, d1.w, w1.w);
        Ws0 += (w0.x + w0.y) + (w0.z + w0.w);
        Ws1 += (w1.x + w1.y) + (w1.z + w1.w);
    }
#undef GATH

    // Pack u = W*x (k<128) and v = s - W*x (k>=128), write swizzled A rows.
    {
        float u[8], v[8];
        u[0] = Ws0 * bflo(x0.x); u[1] = Ws0 * bfhi(x0.x);
        u[2] = Ws0 * bflo(x0.y); u[3] = Ws0 * bfhi(x0.y);
        u[4] = Ws0 * bflo(x0.z); u[5] = Ws0 * bfhi(x0.z);
        u[6] = Ws0 * bflo(x0.w); u[7] = Ws0 * bfhi(x0.w);
        #pragma unroll
        for (int i = 0; i < 8; ++i) v[i] = s0[i] - u[i];
        uint4 up, vp;
        up.x = (unsigned)f2bf(u[0]) | ((unsigned)f2bf(u[1]) << 16);
        up.y = (unsigned)f2bf(u[2]) | ((unsigned)f2bf(u[3]) << 16);
        up.z = (unsigned)f2bf(u[4]) | ((unsigned)f2bf(u[5]) << 16);
        up.w = (unsigned)f2bf(u[6]) | ((unsigned)f2bf(u[7]) << 16);
        vp.x = (unsigned)f2bf(v[0]) | ((unsigned)f2bf(v[1]) << 16);
        vp.y = (unsigned)f2bf(v[2]) | ((unsigned)f2bf(v[3]) << 16);
        vp.z = (unsigned)f2bf(v[4]) | ((unsigned)f2bf(v[5]) << 16);
        vp.w = (unsigned)f2bf(v[6]) | ((unsigned)f2bf(v[7]) << 16);
        const int sw = row0 & 7;
        char* rowp = Asm + row0 * 512;
        *reinterpret_cast<uint4*>(rowp + ((c        ^ sw) * 16)) = up;
        *reinterpret_cast<uint4*>(rowp + (((16 + c) ^ sw) * 16)) = vp;
    }
    {
        float u[8], v[8];
        u[0] = Ws1 * bflo(x1.x); u[1] = Ws1 * bfhi(x1.x);
        u[2] = Ws1 * bflo(x1.y); u[3] = Ws1 * bfhi(x1.y);
        u[4] = Ws1 * bflo(x1.z); u[5] = Ws1 * bfhi(x1.z);
        u[6] = Ws1 * bflo(x1.w); u[7] = Ws1 * bfhi(x1.w);
        #pragma unroll
        for (int i = 0; i < 8; ++i) v[i] = s1[i] - u[i];
        uint4 up, vp;
        up.x = (unsigned)f2bf(u[0]) | ((unsigned)f2bf(u[1]) << 16);
        up.y = (unsigned)f2bf(u[2]) | ((unsigned)f2bf(u[3]) << 16);
        up.z = (unsigned)f2bf(u[4]) | ((unsigned)f2bf(u[5]) << 16);
        up.w = (unsigned)f2bf(u[6]) | ((unsigned)f2bf(u[7]) << 16);
        vp.x = (unsigned)f2bf(v[0]) | ((unsigned)f2bf(v[1]) << 16);
        vp.y = (unsigned)f2bf(v[2]) | ((unsigned)f2bf(v[3]) << 16);
        vp.z = (unsigned)f2bf(v[4]) | ((unsigned)f2bf(v[5]) << 16);
        vp.w = (unsigned)f2bf(v[6]) | ((unsigned)f2bf(v[7]) << 16);
        const int sw = row1 & 7;
        char* rowp = Asm + row1 * 512;
        *reinterpret_cast<uint4*>(rowp + ((c        ^ sw) * 16)) = up;
        *reinterpret_cast<uint4*>(rowp + (((16 + c) ^ sw) * 16)) = vp;
    }
    __syncthreads();

    // ---------------- Phase 2: A[32x256] @ K[256x256], wave = 32x64 tile ----------------
    const int wn = wid;        // 0..3 : 64-col wave tile

    f32x4 acc[2][4];
    #pragma unroll
    for (int mf = 0; mf < 2; ++mf)
        #pragma unroll
        for (int nf = 0; nf < 4; ++nf)
            acc[mf][nf] = (f32x4){0.f, 0.f, 0.f, 0.f};

    #pragma unroll
    for (int ks = 0; ks < 8; ++ks) {     // K = 256 = 8 * 32
        bf16x8 a[2], b[4];
        #pragma unroll
        for (int mf = 0; mf < 2; ++mf) {
            const int r  = mf * 16 + c;
            const int ck = (ks * 4 + g) ^ (r & 7);
            a[mf] = *reinterpret_cast<const bf16x8*>(Asm + r * 512 + ck * 16);
        }
        #pragma unroll
        for (int nf = 0; nf < 4; ++nf) {
            const int nb = wn * 4 + nf;
            b[nf] = *reinterpret_cast<const bf16x8*>(
                btg + (size_t)((nb * 32 + ks * 4 + g) * 16 + c) * 8);  // lane-linear 1KB
        }
        #pragma unroll
        for (int mf = 0; mf < 2; ++mf)
            #pragma unroll
            for (int nf = 0; nf < 4; ++nf)
                acc[mf][nf] = __builtin_amdgcn_mfma_f32_16x16x32_bf16(
                    a[mf], b[nf], acc[mf][nf], 0, 0, 0);
    }

    // Epilogue: C/D layout col = lane&15, row = (lane>>4)*4 + reg. bias ok (Σw==1).
    #pragma unroll
    for (int mf = 0; mf < 2; ++mf) {
        const int row_l = mf * 16 + g * 4;
        #pragma unroll
        for (int nf = 0; nf < 4; ++nf) {
            const int col = wn * 64 + nf * 16 + c;
            const float bb = bias[col];
            #pragma unroll
            for (int r = 0; r < 4; ++r) {
                const int rg = m0 + row_l + r;
                if (rg < V_N)
                    out[(size_t)rg * COUT_N + col] = acc[mf][nf][r] + bb;
            }
        }
    }
}

extern "C" void kernel_launch(void* const* d_in, const int* in_sizes, int n_in,
                              void* d_out, int out_size, void* d_ws, size_t ws_size,
                              hipStream_t stream) {
    const float* data     = (const float*)d_in[0];
    // d_in[1] = edge_src: implicit (vertex i owns edges [16i,16i+16)), unused
    const int*   edge_dst = (const int*)d_in[2];
    const float* edge_w   = (const float*)d_in[3];
    const float* kern     = (const float*)d_in[4];
    const float* bias     = (const float*)d_in[5];
    float*       out      = (float*)d_out;

    unsigned short* bt = (unsigned short*)d_ws;                          // 128KB
    unsigned short* db = (unsigned short*)d_ws + (size_t)K2_N * COUT_N;  // 12.8MB

    prep_bt_kernel<<<K2_N, COUT_N, 0, stream>>>(kern, bt);
    prep_data_kernel<<<(V_N * C_N / 8) / 256, 256, 0, stream>>>(data, db);

    const int nblk = (V_N + 31) / 32;   // 1563
    dgc_fused_kernel<<<nblk, 256, 0, stream>>>(db, edge_dst, edge_w, bt, bias, out);
}

// Round 7
// 140.454 us; speedup vs baseline: 1.2877x; 1.2877x over previous
//
#include <hip/hip_runtime.h>
#include <hip/hip_bf16.h>
#include <cstdint>

#define V_N    50000
#define C_N    128
#define COUT_N 256
#define DEG_N  16
#define K2_N   256   // 2*C

typedef short bf16x8 __attribute__((ext_vector_type(8)));
typedef float f32x4  __attribute__((ext_vector_type(4)));

__device__ __forceinline__ unsigned short f2bf(float f) {
    union { float f; unsigned u; } a; a.f = f;
    unsigned r = a.u + 0x7fffu + ((a.u >> 16) & 1u);   // round-to-nearest-even
    return (unsigned short)(r >> 16);
}
__device__ __forceinline__ float bflo(unsigned p) {
    union { unsigned u; float f; } a; a.u = p << 16; return a.f;
}
__device__ __forceinline__ float bfhi(unsigned p) {
    union { unsigned u; float f; } a; a.u = p & 0xffff0000u; return a.f;
}

// Kernel weights -> bf16, pre-swizzled into MFMA B-fragment order:
// element (n,k) -> bt[ ((nb*8+ks)*4+kk)*128 + nr*8 + kp ]
//   nb=n>>4, nr=n&15, ks=k>>5, kk=(k>>3)&3, kp=k&7
// so a (nf,ks) fragment load is lane-linear 16B -> one coalesced 1KB instr.
__global__ void prep_bt_kernel(const float* __restrict__ kern,
                               unsigned short* __restrict__ bt) {
    const int k = blockIdx.x;    // 0..255
    const int n = threadIdx.x;   // 0..255
    const int idx = (((n >> 4) * 8 + (k >> 5)) * 4 + ((k >> 3) & 3)) * 128
                  + (n & 15) * 8 + (k & 7);
    bt[idx] = f2bf(kern[k * COUT_N + n]);
}

// Convert data fp32 -> bf16 table (halves gather bytes). 12.8MB in d_ws.
__global__ __launch_bounds__(256)
void prep_data_kernel(const float* __restrict__ data,
                      unsigned short* __restrict__ db) {
    const int i = blockIdx.x * 256 + threadIdx.x;        // unit of 8 floats; grid exact
    const float4 f0 = *reinterpret_cast<const float4*>(data + (size_t)i * 8);
    const float4 f1 = *reinterpret_cast<const float4*>(data + (size_t)i * 8 + 4);
    union { unsigned short h[8]; uint4 q; } o;
    o.h[0] = f2bf(f0.x); o.h[1] = f2bf(f0.y); o.h[2] = f2bf(f0.z); o.h[3] = f2bf(f0.w);
    o.h[4] = f2bf(f1.x); o.h[5] = f2bf(f1.y); o.h[6] = f2bf(f1.z); o.h[7] = f2bf(f1.w);
    *reinterpret_cast<uint4*>(db + (size_t)i * 8) = o.q;
}

// Fused: quad-gather weighted aggregation -> bf16 A tile in LDS -> MFMA.
// 256 threads (4 waves), BM = 32 -> grid 1563 (~6 blocks/CU average).
// LDS = A tile 32x512B = 16KB, XOR-swizzled.
//
// launch_bounds history: (512,6) r3 spilled (+180MB scratch); (256,6) r6 spilled
// (WRITE 59->153MB, VGPR squeezed to 40, 94us). The merged two-row gather loop
// needs ~100 live regs; cap must be 128. (256,4): allocator lands ~64-96, no
// spill; at VGPR 64 up to 8 blocks/CU resident -> ~75% occupancy ceiling at
// grid 1563. The BM=32/256-thr shape reached 48% occ even while spilling (r6),
// so residency is proven; this round removes the spill.
__global__ __launch_bounds__(256, 4)
void dgc_fused_kernel(const unsigned short* __restrict__ db,
                      const int* __restrict__ edge_dst,
                      const float* __restrict__ edge_w,
                      const unsigned short* __restrict__ btg,
                      const float* __restrict__ bias,
                      float* __restrict__ out) {
    __shared__ __align__(16) char Asm[32 * 512];   // 16KB

    const int tid  = threadIdx.x;
    const int lane = tid & 63;
    const int wid  = __builtin_amdgcn_readfirstlane(tid >> 6);  // 0..3
    const int m0   = blockIdx.x * 32;
    const int g    = lane >> 4;     // group in wave / k-slice index
    const int c    = lane & 15;     // 16B chunk index

    // ---------------- Phase 1: aggregate 2 rows per 16-lane group ----------------
    const int row0 = wid * 4 + g;        // 0..15
    const int row1 = row0 + 16;          // 16..31
    const int cv0  = min(m0 + row0, V_N - 1);   // clamp: tail rows never stored
    const int cv1  = min(m0 + row1, V_N - 1);

    const uint4*  ed0 = reinterpret_cast<const uint4*>(edge_dst + (size_t)cv0 * DEG_N);
    const float4* ew0 = reinterpret_cast<const float4*>(edge_w  + (size_t)cv0 * DEG_N);
    const uint4*  ed1 = reinterpret_cast<const uint4*>(edge_dst + (size_t)cv1 * DEG_N);
    const float4* ew1 = reinterpret_cast<const float4*>(edge_w  + (size_t)cv1 * DEG_N);

    const uint4 x0 = *reinterpret_cast<const uint4*>(db + (size_t)cv0 * C_N + c * 8);
    const uint4 x1 = *reinterpret_cast<const uint4*>(db + (size_t)cv1 * C_N + c * 8);

    float s0[8], s1[8];
    #pragma unroll
    for (int i = 0; i < 8; ++i) { s0[i] = 0.f; s1[i] = 0.f; }
    float Ws0 = 0.f, Ws1 = 0.f;

#define GATH(S, J, WK)                                                        \
    do {                                                                      \
        const uint4 rr = *reinterpret_cast<const uint4*>(                     \
            db + (size_t)(J) * C_N + c * 8);                                  \
        S[0] = fmaf((WK), bflo(rr.x), S[0]);                                  \
        S[1] = fmaf((WK), bfhi(rr.x), S[1]);                                  \
        S[2] = fmaf((WK), bflo(rr.y), S[2]);                                  \
        S[3] = fmaf((WK), bfhi(rr.y), S[3]);                                  \
        S[4] = fmaf((WK), bflo(rr.z), S[4]);                                  \
        S[5] = fmaf((WK), bfhi(rr.z), S[5]);                                  \
        S[6] = fmaf((WK), bflo(rr.w), S[6]);                                  \
        S[7] = fmaf((WK), bfhi(rr.w), S[7]);                                  \
    } while (0)

    #pragma unroll
    for (int kq = 0; kq < 4; ++kq) {
        const uint4  d0 = ed0[kq];
        const float4 w0 = ew0[kq];
        const uint4  d1 = ed1[kq];
        const float4 w1 = ew1[kq];
        GATH(s0, d0.x, w0.x);
        GATH(s0, d0.y, w0.y);
        GATH(s0, d0.z, w0.z);
        GATH(s0, d0.w, w0.w);
        GATH(s1, d1.x, w1.x);
        GATH(s1, d1.y, w1.y);
        GATH(s1, d1.z, w1.z);
        GATH(s1, d1.w, w1.w);
        Ws0 += (w0.x + w0.y) + (w0.z + w0.w);
        Ws1 += (w1.x + w1.y) + (w1.z + w1.w);
    }
#undef GATH

    // Pack u = W*x (k<128) and v = s - W*x (k>=128), write swizzled A rows.
    {
        float u[8], v[8];
        u[0] = Ws0 * bflo(x0.x); u[1] = Ws0 * bfhi(x0.x);
        u[2] = Ws0 * bflo(x0.y); u[3] = Ws0 * bfhi(x0.y);
        u[4] = Ws0 * bflo(x0.z); u[5] = Ws0 * bfhi(x0.z);
        u[6] = Ws0 * bflo(x0.w); u[7] = Ws0 * bfhi(x0.w);
        #pragma unroll
        for (int i = 0; i < 8; ++i) v[i] = s0[i] - u[i];
        uint4 up, vp;
        up.x = (unsigned)f2bf(u[0]) | ((unsigned)f2bf(u[1]) << 16);
        up.y = (unsigned)f2bf(u[2]) | ((unsigned)f2bf(u[3]) << 16);
        up.z = (unsigned)f2bf(u[4]) | ((unsigned)f2bf(u[5]) << 16);
        up.w = (unsigned)f2bf(u[6]) | ((unsigned)f2bf(u[7]) << 16);
        vp.x = (unsigned)f2bf(v[0]) | ((unsigned)f2bf(v[1]) << 16);
        vp.y = (unsigned)f2bf(v[2]) | ((unsigned)f2bf(v[3]) << 16);
        vp.z = (unsigned)f2bf(v[4]) | ((unsigned)f2bf(v[5]) << 16);
        vp.w = (unsigned)f2bf(v[6]) | ((unsigned)f2bf(v[7]) << 16);
        const int sw = row0 & 7;
        char* rowp = Asm + row0 * 512;
        *reinterpret_cast<uint4*>(rowp + ((c        ^ sw) * 16)) = up;
        *reinterpret_cast<uint4*>(rowp + (((16 + c) ^ sw) * 16)) = vp;
    }
    {
        float u[8], v[8];
        u[0] = Ws1 * bflo(x1.x); u[1] = Ws1 * bfhi(x1.x);
        u[2] = Ws1 * bflo(x1.y); u[3] = Ws1 * bfhi(x1.y);
        u[4] = Ws1 * bflo(x1.z); u[5] = Ws1 * bfhi(x1.z);
        u[6] = Ws1 * bflo(x1.w); u[7] = Ws1 * bfhi(x1.w);
        #pragma unroll
        for (int i = 0; i < 8; ++i) v[i] = s1[i] - u[i];
        uint4 up, vp;
        up.x = (unsigned)f2bf(u[0]) | ((unsigned)f2bf(u[1]) << 16);
        up.y = (unsigned)f2bf(u[2]) | ((unsigned)f2bf(u[3]) << 16);
        up.z = (unsigned)f2bf(u[4]) | ((unsigned)f2bf(u[5]) << 16);
        up.w = (unsigned)f2bf(u[6]) | ((unsigned)f2bf(u[7]) << 16);
        vp.x = (unsigned)f2bf(v[0]) | ((unsigned)f2bf(v[1]) << 16);
        vp.y = (unsigned)f2bf(v[2]) | ((unsigned)f2bf(v[3]) << 16);
        vp.z = (unsigned)f2bf(v[4]) | ((unsigned)f2bf(v[5]) << 16);
        vp.w = (unsigned)f2bf(v[6]) | ((unsigned)f2bf(v[7]) << 16);
        const int sw = row1 & 7;
        char* rowp = Asm + row1 * 512;
        *reinterpret_cast<uint4*>(rowp + ((c        ^ sw) * 16)) = up;
        *reinterpret_cast<uint4*>(rowp + (((16 + c) ^ sw) * 16)) = vp;
    }
    __syncthreads();

    // ---------------- Phase 2: A[32x256] @ K[256x256], wave = 32x64 tile ----------------
    const int wn = wid;        // 0..3 : 64-col wave tile

    f32x4 acc[2][4];
    #pragma unroll
    for (int mf = 0; mf < 2; ++mf)
        #pragma unroll
        for (int nf = 0; nf < 4; ++nf)
            acc[mf][nf] = (f32x4){0.f, 0.f, 0.f, 0.f};

    #pragma unroll
    for (int ks = 0; ks < 8; ++ks) {     // K = 256 = 8 * 32
        bf16x8 a[2], b[4];
        #pragma unroll
        for (int mf = 0; mf < 2; ++mf) {
            const int r  = mf * 16 + c;
            const int ck = (ks * 4 + g) ^ (r & 7);
            a[mf] = *reinterpret_cast<const bf16x8*>(Asm + r * 512 + ck * 16);
        }
        #pragma unroll
        for (int nf = 0; nf < 4; ++nf) {
            const int nb = wn * 4 + nf;
            b[nf] = *reinterpret_cast<const bf16x8*>(
                btg + (size_t)((nb * 32 + ks * 4 + g) * 16 + c) * 8);  // lane-linear 1KB
        }
        #pragma unroll
        for (int mf = 0; mf < 2; ++mf)
            #pragma unroll
            for (int nf = 0; nf < 4; ++nf)
                acc[mf][nf] = __builtin_amdgcn_mfma_f32_16x16x32_bf16(
                    a[mf], b[nf], acc[mf][nf], 0, 0, 0);
    }

    // Epilogue: C/D layout col = lane&15, row = (lane>>4)*4 + reg. bias ok (Σw==1).
    #pragma unroll
    for (int mf = 0; mf < 2; ++mf) {
        const int row_l = mf * 16 + g * 4;
        #pragma unroll
        for (int nf = 0; nf < 4; ++nf) {
            const int col = wn * 64 + nf * 16 + c;
            const float bb = bias[col];
            #pragma unroll
            for (int r = 0; r < 4; ++r) {
                const int rg = m0 + row_l + r;
                if (rg < V_N)
                    out[(size_t)rg * COUT_N + col] = acc[mf][nf][r] + bb;
            }
        }
    }
}

extern "C" void kernel_launch(void* const* d_in, const int* in_sizes, int n_in,
                              void* d_out, int out_size, void* d_ws, size_t ws_size,
                              hipStream_t stream) {
    const float* data     = (const float*)d_in[0];
    // d_in[1] = edge_src: implicit (vertex i owns edges [16i,16i+16)), unused
    const int*   edge_dst = (const int*)d_in[2];
    const float* edge_w   = (const float*)d_in[3];
    const float* kern     = (const float*)d_in[4];
    const float* bias     = (const float*)d_in[5];
    float*       out      = (float*)d_out;

    unsigned short* bt = (unsigned short*)d_ws;                          // 128KB
    unsigned short* db = (unsigned short*)d_ws + (size_t)K2_N * COUT_N;  // 12.8MB

    prep_bt_kernel<<<K2_N, COUT_N, 0, stream>>>(kern, bt);
    prep_data_kernel<<<(V_N * C_N / 8) / 256, 256, 0, stream>>>(data, db);

    const int nblk = (V_N + 31) / 32;   // 1563
    dgc_fused_kernel<<<nblk, 256, 0, stream>>>(db, edge_dst, edge_w, bt, bias, out);
}

// Round 8
// 139.421 us; speedup vs baseline: 1.2972x; 1.0074x over previous
//
#include <hip/hip_runtime.h>
#include <hip/hip_bf16.h>
#include <cstdint>

#define V_N    50000
#define C_N    128
#define COUT_N 256
#define DEG_N  16
#define K2_N   256   // 2*C

typedef short bf16x8 __attribute__((ext_vector_type(8)));
typedef float f32x4  __attribute__((ext_vector_type(4)));

typedef const __attribute__((address_space(1))) void* gas_ptr;
typedef __attribute__((address_space(3))) void*       las_ptr;

__device__ __forceinline__ unsigned short f2bf(float f) {
    union { float f; unsigned u; } a; a.f = f;
    unsigned r = a.u + 0x7fffu + ((a.u >> 16) & 1u);   // round-to-nearest-even
    return (unsigned short)(r >> 16);
}
__device__ __forceinline__ float bflo(unsigned p) {
    union { unsigned u; float f; } a; a.u = p << 16; return a.f;
}
__device__ __forceinline__ float bfhi(unsigned p) {
    union { unsigned u; float f; } a; a.u = p & 0xffff0000u; return a.f;
}

// Merged prep: blocks [0,3125) convert data fp32->bf16 (12.8MB); blocks
// [3125,3381) transpose+convert kernel weights into MFMA B-fragment order.
__global__ __launch_bounds__(256)
void prep_kernel(const float* __restrict__ data, const float* __restrict__ kern,
                 unsigned short* __restrict__ db, unsigned short* __restrict__ bt) {
    const int b = blockIdx.x;
    if (b < 3125) {
        const int i = b * 256 + threadIdx.x;             // unit of 8 floats; exact
        const float4 f0 = *reinterpret_cast<const float4*>(data + (size_t)i * 8);
        const float4 f1 = *reinterpret_cast<const float4*>(data + (size_t)i * 8 + 4);
        union { unsigned short h[8]; uint4 q; } o;
        o.h[0] = f2bf(f0.x); o.h[1] = f2bf(f0.y); o.h[2] = f2bf(f0.z); o.h[3] = f2bf(f0.w);
        o.h[4] = f2bf(f1.x); o.h[5] = f2bf(f1.y); o.h[6] = f2bf(f1.z); o.h[7] = f2bf(f1.w);
        *reinterpret_cast<uint4*>(db + (size_t)i * 8) = o.q;
    } else {
        // element (n,k) -> bt[(((n>>4)*8+(k>>5))*4+((k>>3)&3))*128 + (n&15)*8 + (k&7)]
        const int k = b - 3125;          // 0..255
        const int n = threadIdx.x;       // 0..255
        const int idx = (((n >> 4) * 8 + (k >> 5)) * 4 + ((k >> 3) & 3)) * 128
                      + (n & 15) * 8 + (k & 7);
        bt[idx] = f2bf(kern[k * COUT_N + n]);
    }
}

// Fused kernel, round 8: DMA-staged gathers (global_load_lds, zero VGPR payload).
// 256 thr (4 waves), BM=32, wave owns 8 consecutive rows. Per wave, 4 rounds:
//   issue 8 global_load_lds (each = 4 neighbor rows x 256B = 1KB, per-lane src,
//   linear LDS dst) -> prefetch next round's dst indices -> vmcnt(0) ->
//   accumulate staged rows via ds_read_b32 (stride-4B = 2-way conflict, free).
// Rationale: r2-r7 showed gather time pinned ~50-65us with VGPR-held gathers:
// the allocator pins VGPR=64 -> MLP ~5/wave, and occupancy is stuck ~29%.
// DMA staging moves gather concurrency from the register file to the vmem
// queue (8 x 1KB in flight per wave, no VGPR cost).
// Phase 2 (MFMA, pre-swizzled global Bt) + epilogue identical to round 7.
// LDS: A-tile 32x512B=16KB + staging 4 waves x 8KB = 48KB -> 3 blocks/CU.
__global__ __launch_bounds__(256, 3)
void dgc_fused_kernel(const unsigned short* __restrict__ db,
                      const int* __restrict__ edge_dst,
                      const float* __restrict__ edge_w,
                      const unsigned short* __restrict__ btg,
                      const float* __restrict__ bias,
                      float* __restrict__ out) {
    __shared__ __align__(16) char Asm[32 * 512];      // 16KB A-tile
    __shared__ __align__(16) char Stage[4][8192];     // 32KB gather staging

    const int tid  = threadIdx.x;
    const int lane = tid & 63;
    const int wid  = __builtin_amdgcn_readfirstlane(tid >> 6);  // 0..3
    const int m0   = blockIdx.x * 32;
    const int g    = lane >> 4;       // 16-lane group
    const int c    = lane & 15;       // 16B chunk within a 256B row
    const int vb   = m0 + wid * 8;    // wave's vertex base

    unsigned* stg = reinterpret_cast<unsigned*>(Stage[wid]);   // u32 view

    // ---- preload edge weights: lane holds w[v=lane>>3][lane&7] and [8+(lane&7)]
    const int wv = min(vb + (lane >> 3), V_N - 1);
    const float w0r = edge_w[wv * DEG_N + (lane & 7)];
    const float w1r = edge_w[wv * DEG_N + 8 + (lane & 7)];

    // Wsum per vertex: per-lane pair sum, then butterfly over the 8-lane group
    float wsum = w0r + w1r;
    wsum += __shfl_xor(wsum, 1);
    wsum += __shfl_xor(wsum, 2);
    wsum += __shfl_xor(wsum, 4);      // lanes v*8.. hold Wsum[v]

    // ---- preload own-feature rows: lane l holds channel pair l of each vertex
    unsigned xr[8];
    #pragma unroll
    for (int v = 0; v < 8; ++v) {
        const int cv = min(vb + v, V_N - 1);
        xr[v] = *reinterpret_cast<const unsigned*>(db + (size_t)cv * C_N + lane * 2);
    }

    float s[8][2];
    #pragma unroll
    for (int v = 0; v < 8; ++v) { s[v][0] = 0.f; s[v][1] = 0.f; }

    // ---- round-0 dst indices: DMA instr i stages vertex i, edge r*4+g
    int jbuf[2][8];
    #pragma unroll
    for (int i = 0; i < 8; ++i) {
        const int cv = min(vb + i, V_N - 1);
        jbuf[0][i] = edge_dst[cv * DEG_N + g];          // e = 0*4+g
    }

    #pragma unroll
    for (int r = 0; r < 4; ++r) {
        // issue 8 DMA gathers: per-lane src = row jcur[i], chunk c; dst linear
        #pragma unroll
        for (int i = 0; i < 8; ++i) {
            const unsigned short* src = db + (size_t)jbuf[r & 1][i] * C_N + c * 8;
            __builtin_amdgcn_global_load_lds((gas_ptr)(const void*)src,
                                             (las_ptr)(void*)(Stage[wid] + i * 1024),
                                             16, 0, 0);
        }
        // prefetch next round's dst indices (drained by the vmcnt below)
        if (r < 3) {
            #pragma unroll
            for (int i = 0; i < 8; ++i) {
                const int cv = min(vb + i, V_N - 1);
                jbuf[(r + 1) & 1][i] = edge_dst[cv * DEG_N + (r + 1) * 4 + g];
            }
        }
        asm volatile("s_waitcnt vmcnt(0)" ::: "memory");
        __builtin_amdgcn_sched_barrier(0);
        // accumulate 32 staged rows: row (v,k) at u32 index v*256 + k*64 + lane
        #pragma unroll
        for (int v = 0; v < 8; ++v) {
            #pragma unroll
            for (int k = 0; k < 4; ++k) {
                const unsigned p = stg[v * 256 + k * 64 + lane];
                const float wk = __shfl((r & 2) ? w1r : w0r,
                                        v * 8 + (r & 1) * 4 + k);   // compile-time lane
                s[v][0] = fmaf(wk, bflo(p), s[v][0]);
                s[v][1] = fmaf(wk, bfhi(p), s[v][1]);
            }
        }
    }

    // ---- pack u = W*x (k<128), v = s - W*x (k>=128); write swizzled A rows
    #pragma unroll
    for (int v = 0; v < 8; ++v) {
        const float Ws = __shfl(wsum, v * 8);
        const float ux = Ws * bflo(xr[v]);
        const float uy = Ws * bfhi(xr[v]);
        const float vx = s[v][0] - ux;
        const float vy = s[v][1] - uy;
        const int row = wid * 8 + v;
        const int sw  = row & 7;
        const int cu  = lane >> 2;
        const int within = (lane & 3) * 4;
        char* rowp = Asm + row * 512;
        *reinterpret_cast<unsigned*>(rowp + ((cu        ^ sw) * 16 + within)) =
            (unsigned)f2bf(ux) | ((unsigned)f2bf(uy) << 16);
        *reinterpret_cast<unsigned*>(rowp + (((16 + cu) ^ sw) * 16 + within)) =
            (unsigned)f2bf(vx) | ((unsigned)f2bf(vy) << 16);
    }
    __syncthreads();

    // ---------------- Phase 2: A[32x256] @ K[256x256], wave = 32x64 tile ----------------
    const int wn = wid;

    f32x4 acc[2][4];
    #pragma unroll
    for (int mf = 0; mf < 2; ++mf)
        #pragma unroll
        for (int nf = 0; nf < 4; ++nf)
            acc[mf][nf] = (f32x4){0.f, 0.f, 0.f, 0.f};

    #pragma unroll
    for (int ks = 0; ks < 8; ++ks) {     // K = 256 = 8 * 32
        bf16x8 a[2], b[4];
        #pragma unroll
        for (int mf = 0; mf < 2; ++mf) {
            const int rr = mf * 16 + c;
            const int ck = (ks * 4 + g) ^ (rr & 7);
            a[mf] = *reinterpret_cast<const bf16x8*>(Asm + rr * 512 + ck * 16);
        }
        #pragma unroll
        for (int nf = 0; nf < 4; ++nf) {
            const int nb = wn * 4 + nf;
            b[nf] = *reinterpret_cast<const bf16x8*>(
                btg + (size_t)((nb * 32 + ks * 4 + g) * 16 + c) * 8);  // lane-linear 1KB
        }
        #pragma unroll
        for (int mf = 0; mf < 2; ++mf)
            #pragma unroll
            for (int nf = 0; nf < 4; ++nf)
                acc[mf][nf] = __builtin_amdgcn_mfma_f32_16x16x32_bf16(
                    a[mf], b[nf], acc[mf][nf], 0, 0, 0);
    }

    // Epilogue: C/D layout col = lane&15, row = (lane>>4)*4 + reg. bias ok (Σw==1).
    #pragma unroll
    for (int mf = 0; mf < 2; ++mf) {
        const int row_l = mf * 16 + g * 4;
        #pragma unroll
        for (int nf = 0; nf < 4; ++nf) {
            const int col = wn * 64 + nf * 16 + c;
            const float bb = bias[col];
            #pragma unroll
            for (int r = 0; r < 4; ++r) {
                const int rg = m0 + row_l + r;
                if (rg < V_N)
                    out[(size_t)rg * COUT_N + col] = acc[mf][nf][r] + bb;
            }
        }
    }
}

extern "C" void kernel_launch(void* const* d_in, const int* in_sizes, int n_in,
                              void* d_out, int out_size, void* d_ws, size_t ws_size,
                              hipStream_t stream) {
    const float* data     = (const float*)d_in[0];
    // d_in[1] = edge_src: implicit (vertex i owns edges [16i,16i+16)), unused
    const int*   edge_dst = (const int*)d_in[2];
    const float* edge_w   = (const float*)d_in[3];
    const float* kern     = (const float*)d_in[4];
    const float* bias     = (const float*)d_in[5];
    float*       out      = (float*)d_out;

    unsigned short* bt = (unsigned short*)d_ws;                          // 128KB
    unsigned short* db = (unsigned short*)d_ws + (size_t)K2_N * COUT_N;  // 12.8MB

    prep_kernel<<<3125 + 256, 256, 0, stream>>>(data, kern, db, bt);

    const int nblk = (V_N + 31) / 32;   // 1563
    dgc_fused_kernel<<<nblk, 256, 0, stream>>>(db, edge_dst, edge_w, bt, bias, out);
}

// Round 9
// 124.588 us; speedup vs baseline: 1.4517x; 1.1191x over previous
//
#include <hip/hip_runtime.h>
#include <hip/hip_bf16.h>
#include <cstdint>

#define V_N    50000
#define C_N    128
#define COUT_N 256
#define DEG_N  16
#define K2_N   256   // 2*C

typedef short bf16x8 __attribute__((ext_vector_type(8)));
typedef float f32x4  __attribute__((ext_vector_type(4)));
typedef float f32x2  __attribute__((ext_vector_type(2)));

__device__ __forceinline__ unsigned short f2bf(float f) {
    union { float f; unsigned u; } a; a.f = f;
    unsigned r = a.u + 0x7fffu + ((a.u >> 16) & 1u);   // round-to-nearest-even
    return (unsigned short)(r >> 16);
}

// Merged prep: blocks [0,3125) convert data fp32 -> fp8 e4m3 table (6.4MB);
// blocks [3125,3381) transpose+convert kernel weights to bf16 B-fragment order.
__global__ __launch_bounds__(256)
void prep_kernel(const float* __restrict__ data, const float* __restrict__ kern,
                 unsigned* __restrict__ db8, unsigned short* __restrict__ bt) {
    const int b = blockIdx.x;
    if (b < 3125) {
        const int i = b * 256 + threadIdx.x;             // unit of 8 floats; exact
        const float4 f0 = *reinterpret_cast<const float4*>(data + (size_t)i * 8);
        const float4 f1 = *reinterpret_cast<const float4*>(data + (size_t)i * 8 + 4);
        unsigned lo = 0, hi = 0;
        lo = __builtin_amdgcn_cvt_pk_fp8_f32(f0.x, f0.y, lo, false);  // bytes 0,1
        lo = __builtin_amdgcn_cvt_pk_fp8_f32(f0.z, f0.w, lo, true);   // bytes 2,3
        hi = __builtin_amdgcn_cvt_pk_fp8_f32(f1.x, f1.y, hi, false);
        hi = __builtin_amdgcn_cvt_pk_fp8_f32(f1.z, f1.w, hi, true);
        uint2 o; o.x = lo; o.y = hi;
        *reinterpret_cast<uint2*>(db8 + (size_t)i * 2) = o;
    } else {
        // element (n,k) -> bt[(((n>>4)*8+(k>>5))*4+((k>>3)&3))*128 + (n&15)*8 + (k&7)]
        const int k = b - 3125;          // 0..255
        const int n = threadIdx.x;       // 0..255
        const int idx = (((n >> 4) * 8 + (k >> 5)) * 4 + ((k >> 3) & 3)) * 128
                      + (n & 15) * 8 + (k & 7);
        bt[idx] = f2bf(kern[k * COUT_N + n]);
    }
}

// Fused, round 9 = round-7 structure with an fp8 e4m3 gather table.
// Evidence r1-r8: random-row gather path saturates ~4.5-4.9 TB/s of REQUESTED
// bytes regardless of structure (fp32 410MB->84us, bf16 205MB->47-50us), with
// HBM at 35% and VALU at 20% -> the only lever left is requested bytes.
// fp8 rows are 128B (lane reads uint2, HW v_cvt_pk_f32_fp8 decode); fp32 x_i
// comes from the original `data` (W*x path stays full precision).
// 256 thr (4 waves), BM=32, LDS = A tile 32x512B=16KB XOR-swizzled; phase 2
// (MFMA vs pre-swizzled global Bt) and epilogue verbatim from round 7.
__global__ __launch_bounds__(256, 4)
void dgc_fused_kernel(const float* __restrict__ data,
                      const unsigned char* __restrict__ db8,
                      const int* __restrict__ edge_dst,
                      const float* __restrict__ edge_w,
                      const unsigned short* __restrict__ btg,
                      const float* __restrict__ bias,
                      float* __restrict__ out) {
    __shared__ __align__(16) char Asm[32 * 512];   // 16KB

    const int tid  = threadIdx.x;
    const int lane = tid & 63;
    const int wid  = __builtin_amdgcn_readfirstlane(tid >> 6);  // 0..3
    const int m0   = blockIdx.x * 32;
    const int g    = lane >> 4;     // group in wave / k-slice index
    const int c    = lane & 15;     // chunk index (8 channels per lane)

    // ---------------- Phase 1: aggregate 2 rows per 16-lane group ----------------
    const int row0 = wid * 4 + g;        // 0..15
    const int row1 = row0 + 16;          // 16..31
    const int cv0  = min(m0 + row0, V_N - 1);   // clamp: tail rows never stored
    const int cv1  = min(m0 + row1, V_N - 1);

    const uint4*  ed0 = reinterpret_cast<const uint4*>(edge_dst + (size_t)cv0 * DEG_N);
    const float4* ew0 = reinterpret_cast<const float4*>(edge_w  + (size_t)cv0 * DEG_N);
    const uint4*  ed1 = reinterpret_cast<const uint4*>(edge_dst + (size_t)cv1 * DEG_N);
    const float4* ew1 = reinterpret_cast<const float4*>(edge_w  + (size_t)cv1 * DEG_N);

    // self features (fp32, channels c*8 .. c*8+7)
    const float4 xa0 = *reinterpret_cast<const float4*>(data + (size_t)cv0 * C_N + c * 8);
    const float4 xb0 = *reinterpret_cast<const float4*>(data + (size_t)cv0 * C_N + c * 8 + 4);
    const float4 xa1 = *reinterpret_cast<const float4*>(data + (size_t)cv1 * C_N + c * 8);
    const float4 xb1 = *reinterpret_cast<const float4*>(data + (size_t)cv1 * C_N + c * 8 + 4);

    float s0[8], s1[8];
    #pragma unroll
    for (int i = 0; i < 8; ++i) { s0[i] = 0.f; s1[i] = 0.f; }
    float Ws0 = 0.f, Ws1 = 0.f;

#define GATH(S, J, WK)                                                        \
    do {                                                                      \
        const uint2 rr = *reinterpret_cast<const uint2*>(                     \
            db8 + (size_t)(J) * C_N + c * 8);                                 \
        const f32x2 p0 = __builtin_amdgcn_cvt_pk_f32_fp8(rr.x, false);        \
        const f32x2 p1 = __builtin_amdgcn_cvt_pk_f32_fp8(rr.x, true);         \
        const f32x2 p2 = __builtin_amdgcn_cvt_pk_f32_fp8(rr.y, false);        \
        const f32x2 p3 = __builtin_amdgcn_cvt_pk_f32_fp8(rr.y, true);         \
        S[0] = fmaf((WK), p0[0], S[0]);                                       \
        S[1] = fmaf((WK), p0[1], S[1]);                                       \
        S[2] = fmaf((WK), p1[0], S[2]);                                       \
        S[3] = fmaf((WK), p1[1], S[3]);                                       \
        S[4] = fmaf((WK), p2[0], S[4]);                                       \
        S[5] = fmaf((WK), p2[1], S[5]);                                       \
        S[6] = fmaf((WK), p3[0], S[6]);                                       \
        S[7] = fmaf((WK), p3[1], S[7]);                                       \
    } while (0)

    #pragma unroll
    for (int kq = 0; kq < 4; ++kq) {
        const uint4  d0 = ed0[kq];
        const float4 w0 = ew0[kq];
        const uint4  d1 = ed1[kq];
        const float4 w1 = ew1[kq];
        GATH(s0, d0.x, w0.x);
        GATH(s0, d0.y, w0.y);
        GATH(s0, d0.z, w0.z);
        GATH(s0, d0.w, w0.w);
        GATH(s1, d1.x, w1.x);
        GATH(s1, d1.y, w1.y);
        GATH(s1, d1.z, w1.z);
        GATH(s1, d1.w, w1.w);
        Ws0 += (w0.x + w0.y) + (w0.z + w0.w);
        Ws1 += (w1.x + w1.y) + (w1.z + w1.w);
    }
#undef GATH

    // Pack u = W*x (k<128) and v = s - W*x (k>=128), write swizzled A rows.
    {
        float u[8], v[8];
        u[0] = Ws0 * xa0.x; u[1] = Ws0 * xa0.y; u[2] = Ws0 * xa0.z; u[3] = Ws0 * xa0.w;
        u[4] = Ws0 * xb0.x; u[5] = Ws0 * xb0.y; u[6] = Ws0 * xb0.z; u[7] = Ws0 * xb0.w;
        #pragma unroll
        for (int i = 0; i < 8; ++i) v[i] = s0[i] - u[i];
        uint4 up, vp;
        up.x = (unsigned)f2bf(u[0]) | ((unsigned)f2bf(u[1]) << 16);
        up.y = (unsigned)f2bf(u[2]) | ((unsigned)f2bf(u[3]) << 16);
        up.z = (unsigned)f2bf(u[4]) | ((unsigned)f2bf(u[5]) << 16);
        up.w = (unsigned)f2bf(u[6]) | ((unsigned)f2bf(u[7]) << 16);
        vp.x = (unsigned)f2bf(v[0]) | ((unsigned)f2bf(v[1]) << 16);
        vp.y = (unsigned)f2bf(v[2]) | ((unsigned)f2bf(v[3]) << 16);
        vp.z = (unsigned)f2bf(v[4]) | ((unsigned)f2bf(v[5]) << 16);
        vp.w = (unsigned)f2bf(v[6]) | ((unsigned)f2bf(v[7]) << 16);
        const int sw = row0 & 7;
        char* rowp = Asm + row0 * 512;
        *reinterpret_cast<uint4*>(rowp + ((c        ^ sw) * 16)) = up;
        *reinterpret_cast<uint4*>(rowp + (((16 + c) ^ sw) * 16)) = vp;
    }
    {
        float u[8], v[8];
        u[0] = Ws1 * xa1.x; u[1] = Ws1 * xa1.y; u[2] = Ws1 * xa1.z; u[3] = Ws1 * xa1.w;
        u[4] = Ws1 * xb1.x; u[5] = Ws1 * xb1.y; u[6] = Ws1 * xb1.z; u[7] = Ws1 * xb1.w;
        #pragma unroll
        for (int i = 0; i < 8; ++i) v[i] = s1[i] - u[i];
        uint4 up, vp;
        up.x = (unsigned)f2bf(u[0]) | ((unsigned)f2bf(u[1]) << 16);
        up.y = (unsigned)f2bf(u[2]) | ((unsigned)f2bf(u[3]) << 16);
        up.z = (unsigned)f2bf(u[4]) | ((unsigned)f2bf(u[5]) << 16);
        up.w = (unsigned)f2bf(u[6]) | ((unsigned)f2bf(u[7]) << 16);
        vp.x = (unsigned)f2bf(v[0]) | ((unsigned)f2bf(v[1]) << 16);
        vp.y = (unsigned)f2bf(v[2]) | ((unsigned)f2bf(v[3]) << 16);
        vp.z = (unsigned)f2bf(v[4]) | ((unsigned)f2bf(v[5]) << 16);
        vp.w = (unsigned)f2bf(v[6]) | ((unsigned)f2bf(v[7]) << 16);
        const int sw = row1 & 7;
        char* rowp = Asm + row1 * 512;
        *reinterpret_cast<uint4*>(rowp + ((c        ^ sw) * 16)) = up;
        *reinterpret_cast<uint4*>(rowp + (((16 + c) ^ sw) * 16)) = vp;
    }
    __syncthreads();

    // ---------------- Phase 2: A[32x256] @ K[256x256], wave = 32x64 tile ----------------
    const int wn = wid;        // 0..3 : 64-col wave tile

    f32x4 acc[2][4];
    #pragma unroll
    for (int mf = 0; mf < 2; ++mf)
        #pragma unroll
        for (int nf = 0; nf < 4; ++nf)
            acc[mf][nf] = (f32x4){0.f, 0.f, 0.f, 0.f};

    #pragma unroll
    for (int ks = 0; ks < 8; ++ks) {     // K = 256 = 8 * 32
        bf16x8 a[2], b[4];
        #pragma unroll
        for (int mf = 0; mf < 2; ++mf) {
            const int r  = mf * 16 + c;
            const int ck = (ks * 4 + g) ^ (r & 7);
            a[mf] = *reinterpret_cast<const bf16x8*>(Asm + r * 512 + ck * 16);
        }
        #pragma unroll
        for (int nf = 0; nf < 4; ++nf) {
            const int nb = wn * 4 + nf;
            b[nf] = *reinterpret_cast<const bf16x8*>(
                btg + (size_t)((nb * 32 + ks * 4 + g) * 16 + c) * 8);  // lane-linear 1KB
        }
        #pragma unroll
        for (int mf = 0; mf < 2; ++mf)
            #pragma unroll
            for (int nf = 0; nf < 4; ++nf)
                acc[mf][nf] = __builtin_amdgcn_mfma_f32_16x16x32_bf16(
                    a[mf], b[nf], acc[mf][nf], 0, 0, 0);
    }

    // Epilogue: C/D layout col = lane&15, row = (lane>>4)*4 + reg. bias ok (Σw==1).
    #pragma unroll
    for (int mf = 0; mf < 2; ++mf) {
        const int row_l = mf * 16 + g * 4;
        #pragma unroll
        for (int nf = 0; nf < 4; ++nf) {
            const int col = wn * 64 + nf * 16 + c;
            const float bb = bias[col];
            #pragma unroll
            for (int r = 0; r < 4; ++r) {
                const int rg = m0 + row_l + r;
                if (rg < V_N)
                    out[(size_t)rg * COUT_N + col] = acc[mf][nf][r] + bb;
            }
        }
    }
}

extern "C" void kernel_launch(void* const* d_in, const int* in_sizes, int n_in,
                              void* d_out, int out_size, void* d_ws, size_t ws_size,
                              hipStream_t stream) {
    const float* data     = (const float*)d_in[0];
    // d_in[1] = edge_src: implicit (vertex i owns edges [16i,16i+16)), unused
    const int*   edge_dst = (const int*)d_in[2];
    const float* edge_w   = (const float*)d_in[3];
    const float* kern     = (const float*)d_in[4];
    const float* bias     = (const float*)d_in[5];
    float*       out      = (float*)d_out;

    unsigned short* bt  = (unsigned short*)d_ws;                 // 128KB bf16 B-frags
    unsigned char*  db8 = (unsigned char*)d_ws + 131072;         // 6.4MB fp8 table

    prep_kernel<<<3125 + 256, 256, 0, stream>>>(data, kern, (unsigned*)db8, bt);

    const int nblk = (V_N + 31) / 32;   // 1563
    dgc_fused_kernel<<<nblk, 256, 0, stream>>>(data, db8, edge_dst, edge_w, bt, bias, out);
}